// Round 17
// baseline (201.954 us; speedup 1.0000x reference)
//
#include <hip/hip_runtime.h>

#define BQ 4
#define NH 8
#define NTOK 8448
#define NLAT 256
#define NPTS 8192
#define CDIM 512
#define HD 64
#define SCALE 0.125f
#define L2E 1.4426950408889634f
#define SC2 0.1803368801111204f   // SCALE * log2(e)

typedef __attribute__((ext_vector_type(8))) short short8b;
typedef __attribute__((ext_vector_type(4))) float f32x4;

static __device__ __forceinline__ float4 ld4(const float* p) { return *(const float4*)p; }

static __device__ __forceinline__ short f2b(float f) {
  union { float f; unsigned u; } c; c.f = f;
  unsigned u = c.u;
  u += ((u >> 16) & 1u) + 0x7fffu;   // round-to-nearest-even
  return (short)(u >> 16);
}

static __device__ __forceinline__ float b2f(unsigned short u) {
  union { unsigned u; float f; } c; c.u = ((unsigned)u) << 16; return c.f;
}

static __device__ __forceinline__ int cvtpk(float lo, float hi) {
  int r; asm("v_cvt_pk_bf16_f32 %0, %1, %2" : "=v"(r) : "v"(lo), "v"(hi)); return r;
}

static __device__ __forceinline__ void gload_lds16(const unsigned short* g, unsigned short* l) {
  __builtin_amdgcn_global_load_lds((const __attribute__((address_space(1))) void*)g,
                                   (__attribute__((address_space(3))) void*)l, 16, 0, 0);
}

// ---------------- K0: fused f32 -> bf16 conversion for x, w_qkv, w_proj
__global__ __launch_bounds__(256) void to_bf16_3(const float* __restrict__ a, unsigned short* __restrict__ ao_, int na8,
                                                 const float* __restrict__ b, unsigned short* __restrict__ bo, int nb8,
                                                 const float* __restrict__ c, unsigned short* __restrict__ co, int nc8) {
  int i = blockIdx.x * 256 + threadIdx.x;
  const float* src; unsigned short* dst; int idx;
  if (i < na8) { src = a; dst = ao_; idx = i; }
  else if (i < na8 + nb8) { src = b; dst = bo; idx = i - na8; }
  else if (i < na8 + nb8 + nc8) { src = c; dst = co; idx = i - na8 - nb8; }
  else return;
  float4 x0 = ld4(src + (size_t)idx * 8);
  float4 x1 = ld4(src + (size_t)idx * 8 + 4);
  short8b r;
  r[0] = f2b(x0.x); r[1] = f2b(x0.y); r[2] = f2b(x0.z); r[3] = f2b(x0.w);
  r[4] = f2b(x1.x); r[5] = f2b(x1.y); r[6] = f2b(x1.z); r[7] = f2b(x1.w);
  *(short8b*)&dst[(size_t)idx * 8] = r;
}

// ---------------- K0b: V^T panels (latents only) to global, swizzled layout
// vtg[bh][ (d)*256 + ((l>>3 ^ (d&7))<<3) + (l&7) ] = V[bh][l][d],  l<256
__global__ __launch_bounds__(256) void vtrans(const unsigned short* __restrict__ vb,
                                              unsigned short* __restrict__ vtg) {
  const int bh = blockIdx.x;
  const int n = threadIdx.x;
  const unsigned short* vr = vb + (size_t)bh * NTOK * HD + (size_t)n * HD;
  short8b rv[8];
#pragma unroll
  for (int i = 0; i < 8; ++i) rv[i] = *(const short8b*)(vr + i * 8);
  unsigned short* dst = vtg + (size_t)bh * 16384;
  const int gsw = n >> 3, wi = n & 7;
#pragma unroll
  for (int d0 = 0; d0 < 8; ++d0)
#pragma unroll
    for (int j = 0; j < 8; ++j)
      dst[(d0 * 8 + j) * 256 + ((gsw ^ j) << 3) + wi] = (unsigned short)rv[d0][j];
}

// ---------------- 128x128 / BK=64 counted-vmcnt GEMM template (round-10, verified)
#define STAGE128(PA, PB, kt, s)                                                              \
  do {                                                                                       \
    const int _c = (kt) * 64 + scell;                                                        \
    unsigned short* _d = &lds[(s) * 16384 + t * 8];                                          \
    gload_lds16((PA) + (size_t)(m0 + sr) * CDIM + _c,       _d);                             \
    gload_lds16((PA) + (size_t)(m0 + 32 + sr) * CDIM + _c,  _d + 2048);                      \
    gload_lds16((PA) + (size_t)(m0 + 64 + sr) * CDIM + _c,  _d + 4096);                      \
    gload_lds16((PA) + (size_t)(m0 + 96 + sr) * CDIM + _c,  _d + 6144);                      \
    gload_lds16((PB) + (size_t)(j0 + sr) * CDIM + _c,       _d + 8192);                      \
    gload_lds16((PB) + (size_t)(j0 + 32 + sr) * CDIM + _c,  _d + 10240);                     \
    gload_lds16((PB) + (size_t)(j0 + 64 + sr) * CDIM + _c,  _d + 12288);                     \
    gload_lds16((PB) + (size_t)(j0 + 96 + sr) * CDIM + _c,  _d + 14336);                     \
  } while (0)

#define GEMM128_BODY(PA, PB)                                                                 \
  __shared__ unsigned short lds[32768];                                                      \
  const int fl = blockIdx.y * gridDim.x + blockIdx.x;                                        \
  const int nchunk = (gridDim.x * gridDim.y) >> 3;                                           \
  const int wid = (fl & 7) * nchunk + (fl >> 3);                                             \
  const int m0 = (wid / gridDim.x) * 128;                                                    \
  const int j0 = (wid % gridDim.x) * 128;                                                    \
  const int t = threadIdx.x;                                                                 \
  const int lane = t & 63, wave = t >> 6;                                                    \
  const int wr = wave >> 1, wc = wave & 1;                                                   \
  const int lm = lane & 15, lq = lane >> 4;                                                  \
  const int sr = t >> 3;                                                                     \
  const int scell = (((t & 7) ^ (sr & 7)) << 3);                                             \
  f32x4 acc[4][4] = {};                                                                      \
  STAGE128(PA, PB, 0, 0);                                                                    \
  STAGE128(PA, PB, 1, 1);                                                                    \
  for (int kt = 0; kt < 8; ++kt) {                                                           \
    const int s = kt & 1;                                                                    \
    if (kt == 7) asm volatile("s_waitcnt vmcnt(0)" ::: "memory");                            \
    else         asm volatile("s_waitcnt vmcnt(8)" ::: "memory");                            \
    __builtin_amdgcn_s_barrier();                                                            \
    const unsigned short* sb = &lds[s * 16384];                                              \
    short8b af[4][2], bf[4][2];                                                              \
    _Pragma("unroll")                                                                        \
    for (int mt = 0; mt < 4; ++mt) {                                                         \
      const int RA = wr * 64 + mt * 16 + lm;                                                 \
      const int RB = wc * 64 + mt * 16 + lm;                                                 \
      af[mt][0] = *(const short8b*)&sb[RA * 64 + ((lq ^ (RA & 7)) << 3)];                    \
      af[mt][1] = *(const short8b*)&sb[RA * 64 + (((4 | lq) ^ (RA & 7)) << 3)];              \
      bf[mt][0] = *(const short8b*)&sb[8192 + RB * 64 + ((lq ^ (RB & 7)) << 3)];             \
      bf[mt][1] = *(const short8b*)&sb[8192 + RB * 64 + (((4 | lq) ^ (RB & 7)) << 3)];       \
    }                                                                                        \
    __builtin_amdgcn_s_setprio(1);                                                           \
    _Pragma("unroll")                                                                        \
    for (int ks = 0; ks < 2; ++ks)                                                           \
      _Pragma("unroll")                                                                      \
      for (int mt = 0; mt < 4; ++mt)                                                         \
        _Pragma("unroll")                                                                    \
        for (int nt = 0; nt < 4; ++nt)                                                       \
          acc[mt][nt] = __builtin_amdgcn_mfma_f32_16x16x32_bf16(af[mt][ks], bf[nt][ks],      \
                                                                acc[mt][nt], 0, 0, 0);       \
    __builtin_amdgcn_s_setprio(0);                                                           \
    asm volatile("s_waitcnt lgkmcnt(0)" ::: "memory");                                       \
    __builtin_amdgcn_s_barrier();                                                            \
    __builtin_amdgcn_sched_barrier(0);                                                       \
    if (kt < 6) STAGE128(PA, PB, kt + 2, s);                                                 \
  }

// ---------------- K1: qkv = x @ w_qkv^T, bf16 out scattered to q,k,v [b][h][n][d]
__global__ __launch_bounds__(256, 2) void qkv_mfma(const unsigned short* __restrict__ xb,
                                                   const unsigned short* __restrict__ wb,
                                                   unsigned short* __restrict__ qo,
                                                   unsigned short* __restrict__ ko,
                                                   unsigned short* __restrict__ vo) {
  GEMM128_BODY(xb, wb)
  const int s_ = j0 >> 9;
  unsigned short* dst = (s_ == 0) ? qo : ((s_ == 1) ? ko : vo);
  const int b = m0 / NTOK;
  const int n0 = m0 % NTOK;
  const int h = ((j0 >> 6) + wc) & 7;
#pragma unroll
  for (int mt = 0; mt < 4; ++mt) {
#pragma unroll
    for (int r = 0; r < 4; ++r) {
      const int n = n0 + wr * 64 + mt * 16 + lq * 4 + r;
      const size_t ob = (((size_t)b * NH + h) * NTOK + n) * HD;
#pragma unroll
      for (int nt = 0; nt < 4; ++nt)
        dst[ob + nt * 16 + lm] = (unsigned short)f2b(acc[mt][nt][r]);
    }
  }
}

// ---------------- K5: output = aob @ w_proj^T + b_proj, f32 out
__global__ __launch_bounds__(256, 2) void proj_mfma(const unsigned short* __restrict__ ab,
                                                    const unsigned short* __restrict__ wpb,
                                                    const float* __restrict__ bias,
                                                    float* __restrict__ out) {
  GEMM128_BODY(ab, wpb)
#pragma unroll
  for (int mt = 0; mt < 4; ++mt) {
#pragma unroll
    for (int r = 0; r < 4; ++r) {
      const int m = m0 + wr * 64 + mt * 16 + lq * 4 + r;
#pragma unroll
      for (int nt = 0; nt < 4; ++nt) {
        const int j = j0 + wc * 64 + nt * 16 + lm;
        out[(size_t)m * CDIM + j] = acc[mt][nt][r] + bias[j];
      }
    }
  }
}

// ---------------- K2: points+mean fused attention. K dbuf in LDS (64 KB -> 2 blocks/CU),
// V^T from global (L2). Blocks [0,64): latent; [64,320): points.
__global__ __launch_bounds__(512, 2) void attn_pm(const unsigned short* __restrict__ qb,
                                                  const unsigned short* __restrict__ kb,
                                                  const unsigned short* __restrict__ vb,
                                                  const unsigned short* __restrict__ vtg,
                                                  unsigned short* __restrict__ aob,
                                                  float* __restrict__ out1) {
  __shared__ unsigned short kl[2][16384];   // K permuted rows, slot^=rr&7 swizzle
  const int t = threadIdx.x;
  const int lane = t & 63, wave = t >> 6;
  const int lm = lane & 15, lq = lane >> 4;
  if (blockIdx.x < 64) {
    // ================= latent path (no LDS, V^T from global) =================
    const int idx = blockIdx.x;
    const int bh = idx >> 1, half = idx & 1;
    const size_t bhb = (size_t)bh * NTOK * HD;
    const unsigned short* vtp = vtg + (size_t)bh * 16384;
    const int b = bh >> 3, h = bh & 7;
    const int q0 = half * 128 + wave * 16;
    const size_t qrow = bhb + (size_t)(q0 + lm) * HD;
    const short8b bq0 = *(const short8b*)(qb + qrow + lq * 8);
    const short8b bq1 = *(const short8b*)(qb + qrow + 32 + lq * 8);
    f32x4 s[16] = {};
    __builtin_amdgcn_s_setprio(1);
#pragma unroll
    for (int mt = 0; mt < 16; ++mt) {
      const int krow = ((mt >> 1) << 5) + ((lm >> 2) << 3) + ((mt & 1) << 2) + (lm & 3);
      const unsigned short* kr = kb + bhb + (size_t)krow * HD + lq * 8;
      s[mt] = __builtin_amdgcn_mfma_f32_16x16x32_bf16(*(const short8b*)kr, bq0, s[mt], 0, 0, 0);
      s[mt] = __builtin_amdgcn_mfma_f32_16x16x32_bf16(*(const short8b*)(kr + 32), bq1, s[mt], 0, 0, 0);
    }
    __builtin_amdgcn_s_setprio(0);
    float mx = -1e30f;
#pragma unroll
    for (int mt = 0; mt < 16; ++mt)
#pragma unroll
      for (int r = 0; r < 4; ++r) mx = fmaxf(mx, s[mt][r]);
    mx = fmaxf(mx, __shfl_xor(mx, 16));
    mx = fmaxf(mx, __shfl_xor(mx, 32));
    const float m2 = mx * SCALE * L2E;
    float sum = 0.f;
#pragma unroll
    for (int mt = 0; mt < 16; ++mt)
#pragma unroll
      for (int r = 0; r < 4; ++r) {
        float e = exp2f(fmaf(s[mt][r], SC2, -m2));
        s[mt][r] = e;
        sum += e;
      }
    sum += __shfl_xor(sum, 16);
    sum += __shfl_xor(sum, 32);
    const float inv = 1.f / sum;
#pragma unroll
    for (int mt = 0; mt < 16; ++mt)
#pragma unroll
      for (int r = 0; r < 4; ++r) s[mt][r] *= inv;
    f32x4 o[4] = {};
    __builtin_amdgcn_s_setprio(1);
#pragma unroll
    for (int ks = 0; ks < 8; ++ks) {
      union { int i[4]; short8b v; } af;
      af.i[0] = cvtpk(s[2 * ks][0], s[2 * ks][1]);
      af.i[1] = cvtpk(s[2 * ks][2], s[2 * ks][3]);
      af.i[2] = cvtpk(s[2 * ks + 1][0], s[2 * ks + 1][1]);
      af.i[3] = cvtpk(s[2 * ks + 1][2], s[2 * ks + 1][3]);
#pragma unroll
      for (int ntd = 0; ntd < 4; ++ntd) {
        const int row = ntd * 16 + lm;
        const short8b bv = *(const short8b*)&vtp[row * 256 + ((((ks << 2) | lq) ^ (lm & 7)) << 3)];
        o[ntd] = __builtin_amdgcn_mfma_f32_16x16x32_bf16(af.v, bv, o[ntd], 0, 0, 0);
      }
    }
    __builtin_amdgcn_s_setprio(0);
#pragma unroll
    for (int ntd = 0; ntd < 4; ++ntd)
#pragma unroll
      for (int r = 0; r < 4; ++r) {
        const int n = q0 + lq * 4 + r;
        aob[((size_t)b * NTOK + n) * CDIM + h * HD + ntd * 16 + lm] =
            (unsigned short)f2b(o[ntd][r]);
      }
    return;
  }
  // ================= points + mean path (K dbuf, V^T global) =================
  const int wid = blockIdx.x - 64;             // 0..255
  const int b = wid >> 6, pq = wid & 63;
  const int pp0 = pq * 128 + wave * 16;        // this wave's 16 points
  const size_t bb = (size_t)(b * NH) * NTOK * HD;
#define ISSUE_K(hh, sl_)                                                          \
  do {                                                                            \
    const unsigned short* kg = kb + bb + (size_t)(hh) * NTOK * HD;                \
    _Pragma("unroll")                                                             \
    for (int c = 0; c < 4; ++c) {                                                 \
      const int rr = c * 64 + (t >> 3);                                           \
      const int mt_ = rr >> 4, w_ = rr & 15;                                      \
      const int g = 32 * (mt_ >> 1) + 8 * (w_ >> 2) + 4 * (mt_ & 1) + (w_ & 3);   \
      gload_lds16(kg + g * HD + (((t & 7) ^ (rr & 7)) << 3),                      \
                  &kl[sl_][(c * 512 + t) * 8]);                                   \
    }                                                                             \
  } while (0)
  f32x4 prob[16] = {};
  ISSUE_K(0, 0);
  ISSUE_K(1, 1);
  asm volatile("s_waitcnt vmcnt(0)" ::: "memory");
  __builtin_amdgcn_s_barrier();
  for (int h = 0; h < NH; ++h) {
    const int sl = h & 1;
    const size_t hb = bb + (size_t)h * NTOK * HD;
    const size_t qrow = hb + (size_t)(NLAT + pp0 + lm) * HD;
    const unsigned short* vtp = vtg + (size_t)(b * NH + h) * 16384;
    const short8b bq0 = *(const short8b*)(qb + qrow + lq * 8);
    const short8b bq1 = *(const short8b*)(qb + qrow + 32 + lq * 8);
    f32x4 s[16] = {};
    __builtin_amdgcn_s_setprio(1);
#pragma unroll
    for (int mt = 0; mt < 16; ++mt) {
      const int rr = mt * 16 + lm;
      const short8b ak0 = *(const short8b*)&kl[sl][rr * 64 + ((lq ^ (rr & 7)) << 3)];
      const short8b ak1 = *(const short8b*)&kl[sl][rr * 64 + (((4 | lq) ^ (rr & 7)) << 3)];
      s[mt] = __builtin_amdgcn_mfma_f32_16x16x32_bf16(ak0, bq0, s[mt], 0, 0, 0);
      s[mt] = __builtin_amdgcn_mfma_f32_16x16x32_bf16(ak1, bq1, s[mt], 0, 0, 0);
    }
    __builtin_amdgcn_s_setprio(0);
    float sself = 0.f;
    {
      const unsigned short* qp = qb + qrow + lq * 16;
      const unsigned short* kp = kb + qrow + lq * 16;
      short8b q0 = *(const short8b*)qp, q1 = *(const short8b*)(qp + 8);
      short8b k0 = *(const short8b*)kp, k1 = *(const short8b*)(kp + 8);
#pragma unroll
      for (int j = 0; j < 8; ++j)
        sself += b2f((unsigned short)q0[j]) * b2f((unsigned short)k0[j]) +
                 b2f((unsigned short)q1[j]) * b2f((unsigned short)k1[j]);
    }
    sself += __shfl_xor(sself, 16);
    sself += __shfl_xor(sself, 32);
    sself *= SCALE;
    float mx = -1e30f;
#pragma unroll
    for (int mt = 0; mt < 16; ++mt)
#pragma unroll
      for (int r = 0; r < 4; ++r) mx = fmaxf(mx, s[mt][r]);
    mx = fmaxf(mx, __shfl_xor(mx, 16));
    mx = fmaxf(mx, __shfl_xor(mx, 32));
    const float m = fmaxf(mx * SCALE, sself);
    const float m2 = m * L2E;
    float sum = 0.f;
#pragma unroll
    for (int mt = 0; mt < 16; ++mt)
#pragma unroll
      for (int r = 0; r < 4; ++r) {
        float e = exp2f(fmaf(s[mt][r], SC2, -m2));
        s[mt][r] = e;
        sum += e;
      }
    sum += __shfl_xor(sum, 16);
    sum += __shfl_xor(sum, 32);
    const float pself = exp2f(fmaf(sself, L2E, -m2));
    const float inv = 1.f / (sum + pself);
#pragma unroll
    for (int mt = 0; mt < 16; ++mt)
#pragma unroll
      for (int r = 0; r < 4; ++r) {
        const float pn = s[mt][r] * inv;
        s[mt][r] = pn;
        prob[mt][r] += pn;
      }
    f32x4 o[4] = {};
    __builtin_amdgcn_s_setprio(1);
#pragma unroll
    for (int ks = 0; ks < 8; ++ks) {
      union { int i[4]; short8b v; } af;
      af.i[0] = cvtpk(s[2 * ks][0], s[2 * ks][1]);
      af.i[1] = cvtpk(s[2 * ks][2], s[2 * ks][3]);
      af.i[2] = cvtpk(s[2 * ks + 1][0], s[2 * ks + 1][1]);
      af.i[3] = cvtpk(s[2 * ks + 1][2], s[2 * ks + 1][3]);
#pragma unroll
      for (int ntd = 0; ntd < 4; ++ntd) {
        const int row = ntd * 16 + lm;
        const short8b bv = *(const short8b*)&vtp[row * 256 + ((((ks << 2) | lq) ^ (lm & 7)) << 3)];
        o[ntd] = __builtin_amdgcn_mfma_f32_16x16x32_bf16(af.v, bv, o[ntd], 0, 0, 0);
      }
    }
    __builtin_amdgcn_s_setprio(0);
    const float pisl = pself * inv;
    float psl[4];
#pragma unroll
    for (int r = 0; r < 4; ++r) psl[r] = __shfl(pisl, lq * 4 + r);
#pragma unroll
    for (int ntd = 0; ntd < 4; ++ntd)
#pragma unroll
      for (int r = 0; r < 4; ++r) {
        const int n = NLAT + pp0 + lq * 4 + r;
        const float v_ = b2f(vb[hb + (size_t)n * HD + ntd * 16 + lm]);
        aob[((size_t)b * NTOK + n) * CDIM + h * HD + ntd * 16 + lm] =
            (unsigned short)f2b(o[ntd][r] + psl[r] * v_);
      }
    __builtin_amdgcn_s_barrier();            // all waves done reading kl[sl]
    if (h < 7) {
      asm volatile("s_waitcnt vmcnt(0)" ::: "memory");   // K(h+1) DMA landed (own-wave drain)
      if (h < 6) ISSUE_K(h + 2, sl);         // refill slot sl; flies across head h+1
      __builtin_amdgcn_s_barrier();          // every wave past its drain before reads
    }
  }
  const size_t orow = ((size_t)b * NPTS + pp0 + lm) * NLAT;
#pragma unroll
  for (int mt = 0; mt < 16; ++mt) {
    const int col = 32 * (mt >> 1) + 8 * lq + 4 * (mt & 1);
    *(float4*)&out1[orow + col] = make_float4(prob[mt][0] * 0.125f, prob[mt][1] * 0.125f,
                                              prob[mt][2] * 0.125f, prob[mt][3] * 0.125f);
  }
#undef ISSUE_K
}

extern "C" void kernel_launch(void* const* d_in, const int* in_sizes, int n_in,
                              void* d_out, int out_size, void* d_ws, size_t ws_size,
                              hipStream_t stream) {
  const float* x      = (const float*)d_in[0];
  const float* w_qkv  = (const float*)d_in[1];
  const float* w_proj = (const float*)d_in[2];
  const float* b_proj = (const float*)d_in[3];
  const size_t QSZ = (size_t)BQ * NH * NTOK * HD;   // 17,301,504 elements
  unsigned short* qb  = (unsigned short*)d_ws;
  unsigned short* kb  = qb + QSZ;
  unsigned short* vb  = kb + QSZ;
  unsigned short* aob = vb + QSZ;
  unsigned short* xb  = aob + QSZ;                   // x bf16
  unsigned short* wb  = xb + QSZ;                    // w_qkv bf16 (786432)
  unsigned short* wpb = wb + 786432;                 // w_proj bf16 (262144)
  unsigned short* vtg = wpb + 262144;                // V^T latent panels (524288)
  float* out0 = (float*)d_out;                       // [B][N][C]
  float* out1 = out0 + (size_t)BQ * NTOK * CDIM;     // [B][8192][256]

  to_bf16_3<<<8960, 256, 0, stream>>>(x, xb, 2162688, w_qkv, wb, 98304, w_proj, wpb, 32768);
  qkv_mfma<<<dim3(12, 264), 256, 0, stream>>>(xb, wb, qb, kb, vb);
  vtrans<<<32, 256, 0, stream>>>(vb, vtg);
  attn_pm<<<320, 512, 0, stream>>>(qb, kb, vb, vtg, aob, out1);
  proj_mfma<<<dim3(4, 264), 256, 0, stream>>>(aob, wpb, b_proj, out0);
}

// Round 18
// 192.843 us; speedup vs baseline: 1.0472x; 1.0472x over previous
//
#include <hip/hip_runtime.h>

#define BQ 4
#define NH 8
#define NTOK 8448
#define NLAT 256
#define NPTS 8192
#define CDIM 512
#define HD 64
#define SCALE 0.125f
#define L2E 1.4426950408889634f
#define SC2 0.1803368801111204f   // SCALE * log2(e)

typedef __attribute__((ext_vector_type(8))) short short8b;
typedef __attribute__((ext_vector_type(4))) float f32x4;

static __device__ __forceinline__ float4 ld4(const float* p) { return *(const float4*)p; }

static __device__ __forceinline__ short f2b(float f) {
  union { float f; unsigned u; } c; c.f = f;
  unsigned u = c.u;
  u += ((u >> 16) & 1u) + 0x7fffu;   // round-to-nearest-even
  return (short)(u >> 16);
}

static __device__ __forceinline__ float b2f(unsigned short u) {
  union { unsigned u; float f; } c; c.u = ((unsigned)u) << 16; return c.f;
}

static __device__ __forceinline__ int cvtpk(float lo, float hi) {
  int r; asm("v_cvt_pk_bf16_f32 %0, %1, %2" : "=v"(r) : "v"(lo), "v"(hi)); return r;
}

static __device__ __forceinline__ void gload_lds16(const unsigned short* g, unsigned short* l) {
  __builtin_amdgcn_global_load_lds((const __attribute__((address_space(1))) void*)g,
                                   (__attribute__((address_space(3))) void*)l, 16, 0, 0);
}

// ---------------- K0: fused f32 -> bf16 conversion for x, w_qkv, w_proj
__global__ __launch_bounds__(256) void to_bf16_3(const float* __restrict__ a, unsigned short* __restrict__ ao_, int na8,
                                                 const float* __restrict__ b, unsigned short* __restrict__ bo, int nb8,
                                                 const float* __restrict__ c, unsigned short* __restrict__ co, int nc8) {
  int i = blockIdx.x * 256 + threadIdx.x;
  const float* src; unsigned short* dst; int idx;
  if (i < na8) { src = a; dst = ao_; idx = i; }
  else if (i < na8 + nb8) { src = b; dst = bo; idx = i - na8; }
  else if (i < na8 + nb8 + nc8) { src = c; dst = co; idx = i - na8 - nb8; }
  else return;
  float4 x0 = ld4(src + (size_t)idx * 8);
  float4 x1 = ld4(src + (size_t)idx * 8 + 4);
  short8b r;
  r[0] = f2b(x0.x); r[1] = f2b(x0.y); r[2] = f2b(x0.z); r[3] = f2b(x0.w);
  r[4] = f2b(x1.x); r[5] = f2b(x1.y); r[6] = f2b(x1.z); r[7] = f2b(x1.w);
  *(short8b*)&dst[(size_t)idx * 8] = r;
}

// ---------------- 128x128 / BK=64 counted-vmcnt GEMM template (round-10, verified)
#define STAGE128(PA, PB, kt, s)                                                              \
  do {                                                                                       \
    const int _c = (kt) * 64 + scell;                                                        \
    unsigned short* _d = &lds[(s) * 16384 + t * 8];                                          \
    gload_lds16((PA) + (size_t)(m0 + sr) * CDIM + _c,       _d);                             \
    gload_lds16((PA) + (size_t)(m0 + 32 + sr) * CDIM + _c,  _d + 2048);                      \
    gload_lds16((PA) + (size_t)(m0 + 64 + sr) * CDIM + _c,  _d + 4096);                      \
    gload_lds16((PA) + (size_t)(m0 + 96 + sr) * CDIM + _c,  _d + 6144);                      \
    gload_lds16((PB) + (size_t)(j0 + sr) * CDIM + _c,       _d + 8192);                      \
    gload_lds16((PB) + (size_t)(j0 + 32 + sr) * CDIM + _c,  _d + 10240);                     \
    gload_lds16((PB) + (size_t)(j0 + 64 + sr) * CDIM + _c,  _d + 12288);                     \
    gload_lds16((PB) + (size_t)(j0 + 96 + sr) * CDIM + _c,  _d + 14336);                     \
  } while (0)

#define GEMM128_BODY(PA, PB)                                                                 \
  __shared__ unsigned short lds[32768];                                                      \
  const int fl = blockIdx.y * gridDim.x + blockIdx.x;                                        \
  const int nchunk = (gridDim.x * gridDim.y) >> 3;                                           \
  const int wid = (fl & 7) * nchunk + (fl >> 3);                                             \
  const int m0 = (wid / gridDim.x) * 128;                                                    \
  const int j0 = (wid % gridDim.x) * 128;                                                    \
  const int t = threadIdx.x;                                                                 \
  const int lane = t & 63, wave = t >> 6;                                                    \
  const int wr = wave >> 1, wc = wave & 1;                                                   \
  const int lm = lane & 15, lq = lane >> 4;                                                  \
  const int sr = t >> 3;                                                                     \
  const int scell = (((t & 7) ^ (sr & 7)) << 3);                                             \
  f32x4 acc[4][4] = {};                                                                      \
  STAGE128(PA, PB, 0, 0);                                                                    \
  STAGE128(PA, PB, 1, 1);                                                                    \
  for (int kt = 0; kt < 8; ++kt) {                                                           \
    const int s = kt & 1;                                                                    \
    if (kt == 7) asm volatile("s_waitcnt vmcnt(0)" ::: "memory");                            \
    else         asm volatile("s_waitcnt vmcnt(8)" ::: "memory");                            \
    __builtin_amdgcn_s_barrier();                                                            \
    const unsigned short* sb = &lds[s * 16384];                                              \
    short8b af[4][2], bf[4][2];                                                              \
    _Pragma("unroll")                                                                        \
    for (int mt = 0; mt < 4; ++mt) {                                                         \
      const int RA = wr * 64 + mt * 16 + lm;                                                 \
      const int RB = wc * 64 + mt * 16 + lm;                                                 \
      af[mt][0] = *(const short8b*)&sb[RA * 64 + ((lq ^ (RA & 7)) << 3)];                    \
      af[mt][1] = *(const short8b*)&sb[RA * 64 + (((4 | lq) ^ (RA & 7)) << 3)];              \
      bf[mt][0] = *(const short8b*)&sb[8192 + RB * 64 + ((lq ^ (RB & 7)) << 3)];             \
      bf[mt][1] = *(const short8b*)&sb[8192 + RB * 64 + (((4 | lq) ^ (RB & 7)) << 3)];       \
    }                                                                                        \
    __builtin_amdgcn_s_setprio(1);                                                           \
    _Pragma("unroll")                                                                        \
    for (int ks = 0; ks < 2; ++ks)                                                           \
      _Pragma("unroll")                                                                      \
      for (int mt = 0; mt < 4; ++mt)                                                         \
        _Pragma("unroll")                                                                    \
        for (int nt = 0; nt < 4; ++nt)                                                       \
          acc[mt][nt] = __builtin_amdgcn_mfma_f32_16x16x32_bf16(af[mt][ks], bf[nt][ks],      \
                                                                acc[mt][nt], 0, 0, 0);       \
    __builtin_amdgcn_s_setprio(0);                                                           \
    asm volatile("s_waitcnt lgkmcnt(0)" ::: "memory");                                       \
    __builtin_amdgcn_s_barrier();                                                            \
    __builtin_amdgcn_sched_barrier(0);                                                       \
    if (kt < 6) STAGE128(PA, PB, kt + 2, s);                                                 \
  }

// ---------------- K1: qkv = x @ w_qkv^T, bf16 out scattered to q,k,v [b][h][n][d]
__global__ __launch_bounds__(256, 2) void qkv_mfma(const unsigned short* __restrict__ xb,
                                                   const unsigned short* __restrict__ wb,
                                                   unsigned short* __restrict__ qo,
                                                   unsigned short* __restrict__ ko,
                                                   unsigned short* __restrict__ vo) {
  GEMM128_BODY(xb, wb)
  const int s_ = j0 >> 9;
  unsigned short* dst = (s_ == 0) ? qo : ((s_ == 1) ? ko : vo);
  const int b = m0 / NTOK;
  const int n0 = m0 % NTOK;
  const int h = ((j0 >> 6) + wc) & 7;
#pragma unroll
  for (int mt = 0; mt < 4; ++mt) {
#pragma unroll
    for (int r = 0; r < 4; ++r) {
      const int n = n0 + wr * 64 + mt * 16 + lq * 4 + r;
      const size_t ob = (((size_t)b * NH + h) * NTOK + n) * HD;
#pragma unroll
      for (int nt = 0; nt < 4; ++nt)
        dst[ob + nt * 16 + lm] = (unsigned short)f2b(acc[mt][nt][r]);
    }
  }
}

// ---------------- K5: output = aob @ w_proj^T + b_proj, f32 out
__global__ __launch_bounds__(256, 2) void proj_mfma(const unsigned short* __restrict__ ab,
                                                    const unsigned short* __restrict__ wpb,
                                                    const float* __restrict__ bias,
                                                    float* __restrict__ out) {
  GEMM128_BODY(ab, wpb)
#pragma unroll
  for (int mt = 0; mt < 4; ++mt) {
#pragma unroll
    for (int r = 0; r < 4; ++r) {
      const int m = m0 + wr * 64 + mt * 16 + lq * 4 + r;
#pragma unroll
      for (int nt = 0; nt < 4; ++nt) {
        const int j = j0 + wc * 64 + nt * 16 + lm;
        out[(size_t)m * CDIM + j] = acc[mt][nt][r] + bias[j];
      }
    }
  }
}

// ---------------- K2: points+mean fused attention (exact r13 structure + exp2 softmax).
// Blocks [0,64): latent. Blocks [64,320): points — dbuf K (gload_lds, permuted+swizzled
// source) + V^T (reg-staged) in LDS; normalized-P PV; prob accumulated -> out1.
__global__ __launch_bounds__(512, 2) void attn_pm(const unsigned short* __restrict__ qb,
                                                  const unsigned short* __restrict__ kb,
                                                  const unsigned short* __restrict__ vb,
                                                  unsigned short* __restrict__ aob,
                                                  float* __restrict__ out1) {
  __shared__ unsigned short kl[2][16384];   // K permuted rows, slot^=rr&7 swizzle
  __shared__ unsigned short vt[2][16384];   // V^T: elem(d,l) at d*256 + ((l>>3 ^ (d&7))<<3) + (l&7)
  const int t = threadIdx.x;
  const int lane = t & 63, wave = t >> 6;
  const int lm = lane & 15, lq = lane >> 4;
  if (blockIdx.x < 64) {
    // ================= latent path =================
    const int idx = blockIdx.x;
    const int bh = idx >> 1, half = idx & 1;
    const size_t bhb = (size_t)bh * NTOK * HD;
    {
      const int vr = t >> 1, dh = t & 1;
      const unsigned short* vg = vb + bhb + (size_t)vr * HD + dh * 32;
      short8b rv[4];
#pragma unroll
      for (int i = 0; i < 4; ++i) rv[i] = *(const short8b*)(vg + i * 8);
      const int gsw = vr >> 3, wi = vr & 7;
#pragma unroll
      for (int i = 0; i < 4; ++i) {
        const int d0 = dh * 4 + i;
#pragma unroll
        for (int j = 0; j < 8; ++j)
          vt[0][(d0 * 8 + j) * 256 + ((gsw ^ j) << 3) + wi] = (unsigned short)rv[i][j];
      }
    }
    __syncthreads();
    const int b = bh >> 3, h = bh & 7;
    const int q0 = half * 128 + wave * 16;
    const size_t qrow = bhb + (size_t)(q0 + lm) * HD;
    const short8b bq0 = *(const short8b*)(qb + qrow + lq * 8);
    const short8b bq1 = *(const short8b*)(qb + qrow + 32 + lq * 8);
    f32x4 s[16] = {};
    __builtin_amdgcn_s_setprio(1);
#pragma unroll
    for (int mt = 0; mt < 16; ++mt) {
      const int krow = ((mt >> 1) << 5) + ((lm >> 2) << 3) + ((mt & 1) << 2) + (lm & 3);
      const unsigned short* kr = kb + bhb + (size_t)krow * HD + lq * 8;
      s[mt] = __builtin_amdgcn_mfma_f32_16x16x32_bf16(*(const short8b*)kr, bq0, s[mt], 0, 0, 0);
      s[mt] = __builtin_amdgcn_mfma_f32_16x16x32_bf16(*(const short8b*)(kr + 32), bq1, s[mt], 0, 0, 0);
    }
    __builtin_amdgcn_s_setprio(0);
    float mx = -1e30f;
#pragma unroll
    for (int mt = 0; mt < 16; ++mt)
#pragma unroll
      for (int r = 0; r < 4; ++r) mx = fmaxf(mx, s[mt][r]);
    mx = fmaxf(mx, __shfl_xor(mx, 16));
    mx = fmaxf(mx, __shfl_xor(mx, 32));
    const float m2 = mx * SCALE * L2E;
    float sum = 0.f;
#pragma unroll
    for (int mt = 0; mt < 16; ++mt)
#pragma unroll
      for (int r = 0; r < 4; ++r) {
        float e = exp2f(fmaf(s[mt][r], SC2, -m2));
        s[mt][r] = e;
        sum += e;
      }
    sum += __shfl_xor(sum, 16);
    sum += __shfl_xor(sum, 32);
    const float inv = 1.f / sum;
#pragma unroll
    for (int mt = 0; mt < 16; ++mt)
#pragma unroll
      for (int r = 0; r < 4; ++r) s[mt][r] *= inv;
    f32x4 o[4] = {};
    __builtin_amdgcn_s_setprio(1);
#pragma unroll
    for (int ks = 0; ks < 8; ++ks) {
      union { int i[4]; short8b v; } af;
      af.i[0] = cvtpk(s[2 * ks][0], s[2 * ks][1]);
      af.i[1] = cvtpk(s[2 * ks][2], s[2 * ks][3]);
      af.i[2] = cvtpk(s[2 * ks + 1][0], s[2 * ks + 1][1]);
      af.i[3] = cvtpk(s[2 * ks + 1][2], s[2 * ks + 1][3]);
#pragma unroll
      for (int ntd = 0; ntd < 4; ++ntd) {
        const int row = ntd * 16 + lm;
        const short8b bv = *(const short8b*)&vt[0][row * 256 + ((((ks << 2) | lq) ^ (lm & 7)) << 3)];
        o[ntd] = __builtin_amdgcn_mfma_f32_16x16x32_bf16(af.v, bv, o[ntd], 0, 0, 0);
      }
    }
    __builtin_amdgcn_s_setprio(0);
#pragma unroll
    for (int ntd = 0; ntd < 4; ++ntd)
#pragma unroll
      for (int r = 0; r < 4; ++r) {
        const int n = q0 + lq * 4 + r;
        aob[((size_t)b * NTOK + n) * CDIM + h * HD + ntd * 16 + lm] =
            (unsigned short)f2b(o[ntd][r]);
      }
    return;
  }
  // ================= points + mean path (double-buffered, r13 schedule) =================
  const int bidx = blockIdx.x - 64;            // 0..255
  const int b = bidx >> 6, pq = bidx & 63;
  const int pp0 = pq * 128 + wave * 16;        // this wave's 16 points
  const size_t bb = (size_t)(b * NH) * NTOK * HD;
  const int vr = t >> 1, dh = t & 1;           // V staging split
  const int gsw = vr >> 3, wi = vr & 7;
  short8b vregs[4];
#define ISSUE_K(hh, sl_)                                                          \
  do {                                                                            \
    const unsigned short* kg = kb + bb + (size_t)(hh) * NTOK * HD;                \
    _Pragma("unroll")                                                             \
    for (int c = 0; c < 4; ++c) {                                                 \
      const int rr = c * 64 + (t >> 3);                                           \
      const int mt_ = rr >> 4, w_ = rr & 15;                                      \
      const int g = 32 * (mt_ >> 1) + 8 * (w_ >> 2) + 4 * (mt_ & 1) + (w_ & 3);   \
      gload_lds16(kg + g * HD + (((t & 7) ^ (rr & 7)) << 3),                      \
                  &kl[sl_][(c * 512 + t) * 8]);                                   \
    }                                                                             \
  } while (0)
#define READ_V(hh)                                                                \
  do {                                                                            \
    const unsigned short* vg = vb + bb + (size_t)(hh) * NTOK * HD +               \
                               (size_t)vr * HD + dh * 32;                         \
    _Pragma("unroll")                                                             \
    for (int i = 0; i < 4; ++i) vregs[i] = *(const short8b*)(vg + i * 8);         \
  } while (0)
#define WRITE_V(sl_)                                                              \
  do {                                                                            \
    _Pragma("unroll")                                                             \
    for (int i = 0; i < 4; ++i) {                                                 \
      const int d0 = dh * 4 + i;                                                  \
      _Pragma("unroll")                                                           \
      for (int j = 0; j < 8; ++j)                                                 \
        vt[sl_][(d0 * 8 + j) * 256 + ((gsw ^ j) << 3) + wi] =                     \
            (unsigned short)vregs[i][j];                                          \
    }                                                                             \
  } while (0)
  f32x4 prob[16] = {};
  // prologue
  ISSUE_K(0, 0); READ_V(0);
  asm volatile("s_waitcnt vmcnt(0)" ::: "memory");
  WRITE_V(0);
  ISSUE_K(1, 1); READ_V(1);
  __syncthreads();
  for (int h = 0; h < NH; ++h) {
    const int sl = h & 1;
    const size_t hb = bb + (size_t)h * NTOK * HD;
    const size_t qrow = hb + (size_t)(NLAT + pp0 + lm) * HD;
    const short8b bq0 = *(const short8b*)(qb + qrow + lq * 8);
    const short8b bq1 = *(const short8b*)(qb + qrow + 32 + lq * 8);
    f32x4 s[16] = {};
    __builtin_amdgcn_s_setprio(1);
#pragma unroll
    for (int mt = 0; mt < 16; ++mt) {
      const int rr = mt * 16 + lm;
      const short8b ak0 = *(const short8b*)&kl[sl][rr * 64 + ((lq ^ (rr & 7)) << 3)];
      const short8b ak1 = *(const short8b*)&kl[sl][rr * 64 + (((4 | lq) ^ (rr & 7)) << 3)];
      s[mt] = __builtin_amdgcn_mfma_f32_16x16x32_bf16(ak0, bq0, s[mt], 0, 0, 0);
      s[mt] = __builtin_amdgcn_mfma_f32_16x16x32_bf16(ak1, bq1, s[mt], 0, 0, 0);
    }
    __builtin_amdgcn_s_setprio(0);
    float sself = 0.f;
    {
      const unsigned short* qp = qb + qrow + lq * 16;
      const unsigned short* kp = kb + qrow + lq * 16;
      short8b q0 = *(const short8b*)qp, q1 = *(const short8b*)(qp + 8);
      short8b k0 = *(const short8b*)kp, k1 = *(const short8b*)(kp + 8);
#pragma unroll
      for (int j = 0; j < 8; ++j)
        sself += b2f((unsigned short)q0[j]) * b2f((unsigned short)k0[j]) +
                 b2f((unsigned short)q1[j]) * b2f((unsigned short)k1[j]);
    }
    sself += __shfl_xor(sself, 16);
    sself += __shfl_xor(sself, 32);
    sself *= SCALE;
    float mx = -1e30f;
#pragma unroll
    for (int mt = 0; mt < 16; ++mt)
#pragma unroll
      for (int r = 0; r < 4; ++r) mx = fmaxf(mx, s[mt][r]);
    mx = fmaxf(mx, __shfl_xor(mx, 16));
    mx = fmaxf(mx, __shfl_xor(mx, 32));
    const float m = fmaxf(mx * SCALE, sself);
    const float m2 = m * L2E;
    float sum = 0.f;
#pragma unroll
    for (int mt = 0; mt < 16; ++mt)
#pragma unroll
      for (int r = 0; r < 4; ++r) {
        float e = exp2f(fmaf(s[mt][r], SC2, -m2));
        s[mt][r] = e;
        sum += e;
      }
    sum += __shfl_xor(sum, 16);
    sum += __shfl_xor(sum, 32);
    const float pself = exp2f(fmaf(sself, L2E, -m2));
    const float inv = 1.f / (sum + pself);
    // normalize P, accumulate head-mean
#pragma unroll
    for (int mt = 0; mt < 16; ++mt)
#pragma unroll
      for (int r = 0; r < 4; ++r) {
        const float pn = s[mt][r] * inv;
        s[mt][r] = pn;
        prob[mt][r] += pn;
      }
    f32x4 o[4] = {};
    __builtin_amdgcn_s_setprio(1);
#pragma unroll
    for (int ks = 0; ks < 8; ++ks) {
      union { int i[4]; short8b v; } af;
      af.i[0] = cvtpk(s[2 * ks][0], s[2 * ks][1]);
      af.i[1] = cvtpk(s[2 * ks][2], s[2 * ks][3]);
      af.i[2] = cvtpk(s[2 * ks + 1][0], s[2 * ks + 1][1]);
      af.i[3] = cvtpk(s[2 * ks + 1][2], s[2 * ks + 1][3]);
#pragma unroll
      for (int ntd = 0; ntd < 4; ++ntd) {
        const int row = ntd * 16 + lm;
        const short8b bv = *(const short8b*)&vt[sl][row * 256 + ((((ks << 2) | lq) ^ (lm & 7)) << 3)];
        o[ntd] = __builtin_amdgcn_mfma_f32_16x16x32_bf16(af.v, bv, o[ntd], 0, 0, 0);
      }
    }
    __builtin_amdgcn_s_setprio(0);
    const float pisl = pself * inv;
    float psl[4];
#pragma unroll
    for (int r = 0; r < 4; ++r) psl[r] = __shfl(pisl, lq * 4 + r);
#pragma unroll
    for (int ntd = 0; ntd < 4; ++ntd)
#pragma unroll
      for (int r = 0; r < 4; ++r) {
        const int n = NLAT + pp0 + lq * 4 + r;
        const float v_ = b2f(vb[hb + (size_t)n * HD + ntd * 16 + lm]);
        aob[((size_t)b * NTOK + n) * CDIM + h * HD + ntd * 16 + lm] =
            (unsigned short)f2b(o[ntd][r] + psl[r] * v_);
      }
    __syncthreads();                         // all waves done with slot sl (K+V)
    if (h < 7) {
      asm volatile("s_waitcnt vmcnt(0)" ::: "memory");   // K(h+1) gloads + vregs(h+1) landed
      WRITE_V(sl ^ 1);                       // complete slot sl^1 for next head
      if (h < 6) { ISSUE_K(h + 2, sl); READ_V(h + 2); }
      __syncthreads();
    }
  }
  // write head-mean
  const size_t orow = ((size_t)b * NPTS + pp0 + lm) * NLAT;
#pragma unroll
  for (int mt = 0; mt < 16; ++mt) {
    const int col = 32 * (mt >> 1) + 8 * lq + 4 * (mt & 1);
    *(float4*)&out1[orow + col] = make_float4(prob[mt][0] * 0.125f, prob[mt][1] * 0.125f,
                                              prob[mt][2] * 0.125f, prob[mt][3] * 0.125f);
  }
#undef ISSUE_K
#undef READ_V
#undef WRITE_V
}

extern "C" void kernel_launch(void* const* d_in, const int* in_sizes, int n_in,
                              void* d_out, int out_size, void* d_ws, size_t ws_size,
                              hipStream_t stream) {
  const float* x      = (const float*)d_in[0];
  const float* w_qkv  = (const float*)d_in[1];
  const float* w_proj = (const float*)d_in[2];
  const float* b_proj = (const float*)d_in[3];
  const size_t QSZ = (size_t)BQ * NH * NTOK * HD;   // 17,301,504 elements
  unsigned short* qb  = (unsigned short*)d_ws;
  unsigned short* kb  = qb + QSZ;
  unsigned short* vb  = kb + QSZ;
  unsigned short* aob = vb + QSZ;
  unsigned short* xb  = aob + QSZ;                   // x bf16
  unsigned short* wb  = xb + QSZ;                    // w_qkv bf16 (786432)
  unsigned short* wpb = wb + 786432;                 // w_proj bf16 (262144)
  float* out0 = (float*)d_out;                       // [B][N][C]
  float* out1 = out0 + (size_t)BQ * NTOK * CDIM;     // [B][8192][256]

  to_bf16_3<<<8960, 256, 0, stream>>>(x, xb, 2162688, w_qkv, wb, 98304, w_proj, wpb, 32768);
  qkv_mfma<<<dim3(12, 264), 256, 0, stream>>>(xb, wb, qb, kb, vb);
  attn_pm<<<320, 512, 0, stream>>>(qb, kb, vb, aob, out1);
  proj_mfma<<<dim3(4, 264), 256, 0, stream>>>(aob, wpb, b_proj, out0);
}

// Round 19
// 181.307 us; speedup vs baseline: 1.1139x; 1.0636x over previous
//
#include <hip/hip_runtime.h>

#define BQ 4
#define NH 8
#define NTOK 8448
#define NLAT 256
#define NPTS 8192
#define CDIM 512
#define HD 64
#define SCALE 0.125f
#define L2E 1.4426950408889634f
#define SC2 0.1803368801111204f   // SCALE * log2(e)

typedef __attribute__((ext_vector_type(8))) short short8b;
typedef __attribute__((ext_vector_type(4))) float f32x4;

static __device__ __forceinline__ float4 ld4(const float* p) { return *(const float4*)p; }

static __device__ __forceinline__ short f2b(float f) {
  union { float f; unsigned u; } c; c.f = f;
  unsigned u = c.u;
  u += ((u >> 16) & 1u) + 0x7fffu;   // round-to-nearest-even
  return (short)(u >> 16);
}

static __device__ __forceinline__ float b2f(unsigned short u) {
  union { unsigned u; float f; } c; c.u = ((unsigned)u) << 16; return c.f;
}

static __device__ __forceinline__ int cvtpk(float lo, float hi) {
  int r; asm("v_cvt_pk_bf16_f32 %0, %1, %2" : "=v"(r) : "v"(lo), "v"(hi)); return r;
}

// raw hardware 2^x (v_exp_f32) — avoids __ocml_exp2_f32's denormal branch
static __device__ __forceinline__ float fexp2(float x) {
  float r; asm("v_exp_f32 %0, %1" : "=v"(r) : "v"(x)); return r;
}

static __device__ __forceinline__ void gload_lds16(const unsigned short* g, unsigned short* l) {
  __builtin_amdgcn_global_load_lds((const __attribute__((address_space(1))) void*)g,
                                   (__attribute__((address_space(3))) void*)l, 16, 0, 0);
}

// ---------------- K0: fused f32 -> bf16 conversion for x, w_qkv, w_proj
__global__ __launch_bounds__(256) void to_bf16_3(const float* __restrict__ a, unsigned short* __restrict__ ao_, int na8,
                                                 const float* __restrict__ b, unsigned short* __restrict__ bo, int nb8,
                                                 const float* __restrict__ c, unsigned short* __restrict__ co, int nc8) {
  int i = blockIdx.x * 256 + threadIdx.x;
  const float* src; unsigned short* dst; int idx;
  if (i < na8) { src = a; dst = ao_; idx = i; }
  else if (i < na8 + nb8) { src = b; dst = bo; idx = i - na8; }
  else if (i < na8 + nb8 + nc8) { src = c; dst = co; idx = i - na8 - nb8; }
  else return;
  float4 x0 = ld4(src + (size_t)idx * 8);
  float4 x1 = ld4(src + (size_t)idx * 8 + 4);
  short8b r;
  r[0] = f2b(x0.x); r[1] = f2b(x0.y); r[2] = f2b(x0.z); r[3] = f2b(x0.w);
  r[4] = f2b(x1.x); r[5] = f2b(x1.y); r[6] = f2b(x1.z); r[7] = f2b(x1.w);
  *(short8b*)&dst[(size_t)idx * 8] = r;
}

// ---------------- 128x128 / BK=64 counted-vmcnt GEMM template (round-10, verified)
#define STAGE128(PA, PB, kt, s)                                                              \
  do {                                                                                       \
    const int _c = (kt) * 64 + scell;                                                        \
    unsigned short* _d = &lds[(s) * 16384 + t * 8];                                          \
    gload_lds16((PA) + (size_t)(m0 + sr) * CDIM + _c,       _d);                             \
    gload_lds16((PA) + (size_t)(m0 + 32 + sr) * CDIM + _c,  _d + 2048);                      \
    gload_lds16((PA) + (size_t)(m0 + 64 + sr) * CDIM + _c,  _d + 4096);                      \
    gload_lds16((PA) + (size_t)(m0 + 96 + sr) * CDIM + _c,  _d + 6144);                      \
    gload_lds16((PB) + (size_t)(j0 + sr) * CDIM + _c,       _d + 8192);                      \
    gload_lds16((PB) + (size_t)(j0 + 32 + sr) * CDIM + _c,  _d + 10240);                     \
    gload_lds16((PB) + (size_t)(j0 + 64 + sr) * CDIM + _c,  _d + 12288);                     \
    gload_lds16((PB) + (size_t)(j0 + 96 + sr) * CDIM + _c,  _d + 14336);                     \
  } while (0)

#define GEMM128_BODY(PA, PB)                                                                 \
  __shared__ unsigned short lds[32768];                                                      \
  const int fl = blockIdx.y * gridDim.x + blockIdx.x;                                        \
  const int nchunk = (gridDim.x * gridDim.y) >> 3;                                           \
  const int wid = (fl & 7) * nchunk + (fl >> 3);                                             \
  const int m0 = (wid / gridDim.x) * 128;                                                    \
  const int j0 = (wid % gridDim.x) * 128;                                                    \
  const int t = threadIdx.x;                                                                 \
  const int lane = t & 63, wave = t >> 6;                                                    \
  const int wr = wave >> 1, wc = wave & 1;                                                   \
  const int lm = lane & 15, lq = lane >> 4;                                                  \
  const int sr = t >> 3;                                                                     \
  const int scell = (((t & 7) ^ (sr & 7)) << 3);                                             \
  f32x4 acc[4][4] = {};                                                                      \
  STAGE128(PA, PB, 0, 0);                                                                    \
  STAGE128(PA, PB, 1, 1);                                                                    \
  for (int kt = 0; kt < 8; ++kt) {                                                           \
    const int s = kt & 1;                                                                    \
    if (kt == 7) asm volatile("s_waitcnt vmcnt(0)" ::: "memory");                            \
    else         asm volatile("s_waitcnt vmcnt(8)" ::: "memory");                            \
    __builtin_amdgcn_s_barrier();                                                            \
    const unsigned short* sb = &lds[s * 16384];                                              \
    short8b af[4][2], bf[4][2];                                                              \
    _Pragma("unroll")                                                                        \
    for (int mt = 0; mt < 4; ++mt) {                                                         \
      const int RA = wr * 64 + mt * 16 + lm;                                                 \
      const int RB = wc * 64 + mt * 16 + lm;                                                 \
      af[mt][0] = *(const short8b*)&sb[RA * 64 + ((lq ^ (RA & 7)) << 3)];                    \
      af[mt][1] = *(const short8b*)&sb[RA * 64 + (((4 | lq) ^ (RA & 7)) << 3)];              \
      bf[mt][0] = *(const short8b*)&sb[8192 + RB * 64 + ((lq ^ (RB & 7)) << 3)];             \
      bf[mt][1] = *(const short8b*)&sb[8192 + RB * 64 + (((4 | lq) ^ (RB & 7)) << 3)];       \
    }                                                                                        \
    __builtin_amdgcn_s_setprio(1);                                                           \
    _Pragma("unroll")                                                                        \
    for (int ks = 0; ks < 2; ++ks)                                                           \
      _Pragma("unroll")                                                                      \
      for (int mt = 0; mt < 4; ++mt)                                                         \
        _Pragma("unroll")                                                                    \
        for (int nt = 0; nt < 4; ++nt)                                                       \
          acc[mt][nt] = __builtin_amdgcn_mfma_f32_16x16x32_bf16(af[mt][ks], bf[nt][ks],      \
                                                                acc[mt][nt], 0, 0, 0);       \
    __builtin_amdgcn_s_setprio(0);                                                           \
    asm volatile("s_waitcnt lgkmcnt(0)" ::: "memory");                                       \
    __builtin_amdgcn_s_barrier();                                                            \
    __builtin_amdgcn_sched_barrier(0);                                                       \
    if (kt < 6) STAGE128(PA, PB, kt + 2, s);                                                 \
  }

// ---------------- K1: qkv = x @ w_qkv^T, bf16 out scattered to q,k,v [b][h][n][d]
__global__ __launch_bounds__(256, 2) void qkv_mfma(const unsigned short* __restrict__ xb,
                                                   const unsigned short* __restrict__ wb,
                                                   unsigned short* __restrict__ qo,
                                                   unsigned short* __restrict__ ko,
                                                   unsigned short* __restrict__ vo) {
  GEMM128_BODY(xb, wb)
  const int s_ = j0 >> 9;
  unsigned short* dst = (s_ == 0) ? qo : ((s_ == 1) ? ko : vo);
  const int b = m0 / NTOK;
  const int n0 = m0 % NTOK;
  const int h = ((j0 >> 6) + wc) & 7;
#pragma unroll
  for (int mt = 0; mt < 4; ++mt) {
#pragma unroll
    for (int r = 0; r < 4; ++r) {
      const int n = n0 + wr * 64 + mt * 16 + lq * 4 + r;
      const size_t ob = (((size_t)b * NH + h) * NTOK + n) * HD;
#pragma unroll
      for (int nt = 0; nt < 4; ++nt)
        dst[ob + nt * 16 + lm] = (unsigned short)f2b(acc[mt][nt][r]);
    }
  }
}

// ---------------- K5: output = aob @ w_proj^T + b_proj, f32 out
__global__ __launch_bounds__(256, 2) void proj_mfma(const unsigned short* __restrict__ ab,
                                                    const unsigned short* __restrict__ wpb,
                                                    const float* __restrict__ bias,
                                                    float* __restrict__ out) {
  GEMM128_BODY(ab, wpb)
#pragma unroll
  for (int mt = 0; mt < 4; ++mt) {
#pragma unroll
    for (int r = 0; r < 4; ++r) {
      const int m = m0 + wr * 64 + mt * 16 + lq * 4 + r;
#pragma unroll
      for (int nt = 0; nt < 4; ++nt) {
        const int j = j0 + wc * 64 + nt * 16 + lm;
        out[(size_t)m * CDIM + j] = acc[mt][nt][r] + bias[j];
      }
    }
  }
}

// ---------------- K2: points+mean fused attention (r13 structure, hw-exp2 softmax).
// Blocks [0,64): latent. Blocks [64,320): points — dbuf K (gload_lds, permuted+swizzled
// source) + V^T (reg-staged) in LDS; normalized-P PV; prob accumulated -> out1.
__global__ __launch_bounds__(512, 2) void attn_pm(const unsigned short* __restrict__ qb,
                                                  const unsigned short* __restrict__ kb,
                                                  const unsigned short* __restrict__ vb,
                                                  unsigned short* __restrict__ aob,
                                                  float* __restrict__ out1) {
  __shared__ unsigned short kl[2][16384];   // K permuted rows, slot^=rr&7 swizzle
  __shared__ unsigned short vt[2][16384];   // V^T: elem(d,l) at d*256 + ((l>>3 ^ (d&7))<<3) + (l&7)
  const int t = threadIdx.x;
  const int lane = t & 63, wave = t >> 6;
  const int lm = lane & 15, lq = lane >> 4;
  if (blockIdx.x < 64) {
    // ================= latent path =================
    const int idx = blockIdx.x;
    const int bh = idx >> 1, half = idx & 1;
    const size_t bhb = (size_t)bh * NTOK * HD;
    {
      const int vr = t >> 1, dh = t & 1;
      const unsigned short* vg = vb + bhb + (size_t)vr * HD + dh * 32;
      short8b rv[4];
#pragma unroll
      for (int i = 0; i < 4; ++i) rv[i] = *(const short8b*)(vg + i * 8);
      const int gsw = vr >> 3, wi = vr & 7;
#pragma unroll
      for (int i = 0; i < 4; ++i) {
        const int d0 = dh * 4 + i;
#pragma unroll
        for (int j = 0; j < 8; ++j)
          vt[0][(d0 * 8 + j) * 256 + ((gsw ^ j) << 3) + wi] = (unsigned short)rv[i][j];
      }
    }
    __syncthreads();
    const int b = bh >> 3, h = bh & 7;
    const int q0 = half * 128 + wave * 16;
    const size_t qrow = bhb + (size_t)(q0 + lm) * HD;
    const short8b bq0 = *(const short8b*)(qb + qrow + lq * 8);
    const short8b bq1 = *(const short8b*)(qb + qrow + 32 + lq * 8);
    f32x4 s[16] = {};
    __builtin_amdgcn_s_setprio(1);
#pragma unroll
    for (int mt = 0; mt < 16; ++mt) {
      const int krow = ((mt >> 1) << 5) + ((lm >> 2) << 3) + ((mt & 1) << 2) + (lm & 3);
      const unsigned short* kr = kb + bhb + (size_t)krow * HD + lq * 8;
      s[mt] = __builtin_amdgcn_mfma_f32_16x16x32_bf16(*(const short8b*)kr, bq0, s[mt], 0, 0, 0);
      s[mt] = __builtin_amdgcn_mfma_f32_16x16x32_bf16(*(const short8b*)(kr + 32), bq1, s[mt], 0, 0, 0);
    }
    __builtin_amdgcn_s_setprio(0);
    float mx = -1e30f;
#pragma unroll
    for (int mt = 0; mt < 16; ++mt)
#pragma unroll
      for (int r = 0; r < 4; ++r) mx = fmaxf(mx, s[mt][r]);
    mx = fmaxf(mx, __shfl_xor(mx, 16));
    mx = fmaxf(mx, __shfl_xor(mx, 32));
    const float m2 = mx * SCALE * L2E;
    float sum = 0.f;
#pragma unroll
    for (int mt = 0; mt < 16; ++mt)
#pragma unroll
      for (int r = 0; r < 4; ++r) {
        float e = fexp2(fmaf(s[mt][r], SC2, -m2));
        s[mt][r] = e;
        sum += e;
      }
    sum += __shfl_xor(sum, 16);
    sum += __shfl_xor(sum, 32);
    const float inv = 1.f / sum;
#pragma unroll
    for (int mt = 0; mt < 16; ++mt)
#pragma unroll
      for (int r = 0; r < 4; ++r) s[mt][r] *= inv;
    f32x4 o[4] = {};
    __builtin_amdgcn_s_setprio(1);
#pragma unroll
    for (int ks = 0; ks < 8; ++ks) {
      union { int i[4]; short8b v; } af;
      af.i[0] = cvtpk(s[2 * ks][0], s[2 * ks][1]);
      af.i[1] = cvtpk(s[2 * ks][2], s[2 * ks][3]);
      af.i[2] = cvtpk(s[2 * ks + 1][0], s[2 * ks + 1][1]);
      af.i[3] = cvtpk(s[2 * ks + 1][2], s[2 * ks + 1][3]);
#pragma unroll
      for (int ntd = 0; ntd < 4; ++ntd) {
        const int row = ntd * 16 + lm;
        const short8b bv = *(const short8b*)&vt[0][row * 256 + ((((ks << 2) | lq) ^ (lm & 7)) << 3)];
        o[ntd] = __builtin_amdgcn_mfma_f32_16x16x32_bf16(af.v, bv, o[ntd], 0, 0, 0);
      }
    }
    __builtin_amdgcn_s_setprio(0);
#pragma unroll
    for (int ntd = 0; ntd < 4; ++ntd)
#pragma unroll
      for (int r = 0; r < 4; ++r) {
        const int n = q0 + lq * 4 + r;
        aob[((size_t)b * NTOK + n) * CDIM + h * HD + ntd * 16 + lm] =
            (unsigned short)f2b(o[ntd][r]);
      }
    return;
  }
  // ================= points + mean path (double-buffered, r13 schedule) =================
  const int bidx = blockIdx.x - 64;            // 0..255
  const int b = bidx >> 6, pq = bidx & 63;
  const int pp0 = pq * 128 + wave * 16;        // this wave's 16 points
  const size_t bb = (size_t)(b * NH) * NTOK * HD;
  const int vr = t >> 1, dh = t & 1;           // V staging split
  const int gsw = vr >> 3, wi = vr & 7;
  short8b vregs[4];
#define ISSUE_K(hh, sl_)                                                          \
  do {                                                                            \
    const unsigned short* kg = kb + bb + (size_t)(hh) * NTOK * HD;                \
    _Pragma("unroll")                                                             \
    for (int c = 0; c < 4; ++c) {                                                 \
      const int rr = c * 64 + (t >> 3);                                           \
      const int mt_ = rr >> 4, w_ = rr & 15;                                      \
      const int g = 32 * (mt_ >> 1) + 8 * (w_ >> 2) + 4 * (mt_ & 1) + (w_ & 3);   \
      gload_lds16(kg + g * HD + (((t & 7) ^ (rr & 7)) << 3),                      \
                  &kl[sl_][(c * 512 + t) * 8]);                                   \
    }                                                                             \
  } while (0)
#define READ_V(hh)                                                                \
  do {                                                                            \
    const unsigned short* vg = vb + bb + (size_t)(hh) * NTOK * HD +               \
                               (size_t)vr * HD + dh * 32;                         \
    _Pragma("unroll")                                                             \
    for (int i = 0; i < 4; ++i) vregs[i] = *(const short8b*)(vg + i * 8);         \
  } while (0)
#define WRITE_V(sl_)                                                              \
  do {                                                                            \
    _Pragma("unroll")                                                             \
    for (int i = 0; i < 4; ++i) {                                                 \
      const int d0 = dh * 4 + i;                                                  \
      _Pragma("unroll")                                                           \
      for (int j = 0; j < 8; ++j)                                                 \
        vt[sl_][(d0 * 8 + j) * 256 + ((gsw ^ j) << 3) + wi] =                     \
            (unsigned short)vregs[i][j];                                          \
    }                                                                             \
  } while (0)
  f32x4 prob[16] = {};
  // prologue
  ISSUE_K(0, 0); READ_V(0);
  asm volatile("s_waitcnt vmcnt(0)" ::: "memory");
  WRITE_V(0);
  ISSUE_K(1, 1); READ_V(1);
  __syncthreads();
  for (int h = 0; h < NH; ++h) {
    const int sl = h & 1;
    const size_t hb = bb + (size_t)h * NTOK * HD;
    const size_t qrow = hb + (size_t)(NLAT + pp0 + lm) * HD;
    const short8b bq0 = *(const short8b*)(qb + qrow + lq * 8);
    const short8b bq1 = *(const short8b*)(qb + qrow + 32 + lq * 8);
    f32x4 s[16] = {};
    __builtin_amdgcn_s_setprio(1);
#pragma unroll
    for (int mt = 0; mt < 16; ++mt) {
      const int rr = mt * 16 + lm;
      const short8b ak0 = *(const short8b*)&kl[sl][rr * 64 + ((lq ^ (rr & 7)) << 3)];
      const short8b ak1 = *(const short8b*)&kl[sl][rr * 64 + (((4 | lq) ^ (rr & 7)) << 3)];
      s[mt] = __builtin_amdgcn_mfma_f32_16x16x32_bf16(ak0, bq0, s[mt], 0, 0, 0);
      s[mt] = __builtin_amdgcn_mfma_f32_16x16x32_bf16(ak1, bq1, s[mt], 0, 0, 0);
    }
    __builtin_amdgcn_s_setprio(0);
    float sself = 0.f;
    {
      const unsigned short* qp = qb + qrow + lq * 16;
      const unsigned short* kp = kb + qrow + lq * 16;
      short8b q0 = *(const short8b*)qp, q1 = *(const short8b*)(qp + 8);
      short8b k0 = *(const short8b*)kp, k1 = *(const short8b*)(kp + 8);
#pragma unroll
      for (int j = 0; j < 8; ++j)
        sself += b2f((unsigned short)q0[j]) * b2f((unsigned short)k0[j]) +
                 b2f((unsigned short)q1[j]) * b2f((unsigned short)k1[j]);
    }
    sself += __shfl_xor(sself, 16);
    sself += __shfl_xor(sself, 32);
    sself *= SCALE;
    float mx = -1e30f;
#pragma unroll
    for (int mt = 0; mt < 16; ++mt)
#pragma unroll
      for (int r = 0; r < 4; ++r) mx = fmaxf(mx, s[mt][r]);
    mx = fmaxf(mx, __shfl_xor(mx, 16));
    mx = fmaxf(mx, __shfl_xor(mx, 32));
    const float m = fmaxf(mx * SCALE, sself);
    const float m2 = m * L2E;
    float sum = 0.f;
#pragma unroll
    for (int mt = 0; mt < 16; ++mt)
#pragma unroll
      for (int r = 0; r < 4; ++r) {
        float e = fexp2(fmaf(s[mt][r], SC2, -m2));
        s[mt][r] = e;
        sum += e;
      }
    sum += __shfl_xor(sum, 16);
    sum += __shfl_xor(sum, 32);
    const float pself = fexp2(fmaf(sself, L2E, -m2));
    const float inv = 1.f / (sum + pself);
    // normalize P, accumulate head-mean
#pragma unroll
    for (int mt = 0; mt < 16; ++mt)
#pragma unroll
      for (int r = 0; r < 4; ++r) {
        const float pn = s[mt][r] * inv;
        s[mt][r] = pn;
        prob[mt][r] += pn;
      }
    f32x4 o[4] = {};
    __builtin_amdgcn_s_setprio(1);
#pragma unroll
    for (int ks = 0; ks < 8; ++ks) {
      union { int i[4]; short8b v; } af;
      af.i[0] = cvtpk(s[2 * ks][0], s[2 * ks][1]);
      af.i[1] = cvtpk(s[2 * ks][2], s[2 * ks][3]);
      af.i[2] = cvtpk(s[2 * ks + 1][0], s[2 * ks + 1][1]);
      af.i[3] = cvtpk(s[2 * ks + 1][2], s[2 * ks + 1][3]);
#pragma unroll
      for (int ntd = 0; ntd < 4; ++ntd) {
        const int row = ntd * 16 + lm;
        const short8b bv = *(const short8b*)&vt[sl][row * 256 + ((((ks << 2) | lq) ^ (lm & 7)) << 3)];
        o[ntd] = __builtin_amdgcn_mfma_f32_16x16x32_bf16(af.v, bv, o[ntd], 0, 0, 0);
      }
    }
    __builtin_amdgcn_s_setprio(0);
    const float pisl = pself * inv;
    float psl[4];
#pragma unroll
    for (int r = 0; r < 4; ++r) psl[r] = __shfl(pisl, lq * 4 + r);
#pragma unroll
    for (int ntd = 0; ntd < 4; ++ntd)
#pragma unroll
      for (int r = 0; r < 4; ++r) {
        const int n = NLAT + pp0 + lq * 4 + r;
        const float v_ = b2f(vb[hb + (size_t)n * HD + ntd * 16 + lm]);
        aob[((size_t)b * NTOK + n) * CDIM + h * HD + ntd * 16 + lm] =
            (unsigned short)f2b(o[ntd][r] + psl[r] * v_);
      }
    __syncthreads();                         // all waves done with slot sl (K+V)
    if (h < 7) {
      asm volatile("s_waitcnt vmcnt(0)" ::: "memory");   // K(h+1) gloads + vregs(h+1) landed
      WRITE_V(sl ^ 1);                       // complete slot sl^1 for next head
      if (h < 6) { ISSUE_K(h + 2, sl); READ_V(h + 2); }
      __syncthreads();
    }
  }
  // write head-mean
  const size_t orow = ((size_t)b * NPTS + pp0 + lm) * NLAT;
#pragma unroll
  for (int mt = 0; mt < 16; ++mt) {
    const int col = 32 * (mt >> 1) + 8 * lq + 4 * (mt & 1);
    *(float4*)&out1[orow + col] = make_float4(prob[mt][0] * 0.125f, prob[mt][1] * 0.125f,
                                              prob[mt][2] * 0.125f, prob[mt][3] * 0.125f);
  }
#undef ISSUE_K
#undef READ_V
#undef WRITE_V
}

extern "C" void kernel_launch(void* const* d_in, const int* in_sizes, int n_in,
                              void* d_out, int out_size, void* d_ws, size_t ws_size,
                              hipStream_t stream) {
  const float* x      = (const float*)d_in[0];
  const float* w_qkv  = (const float*)d_in[1];
  const float* w_proj = (const float*)d_in[2];
  const float* b_proj = (const float*)d_in[3];
  const size_t QSZ = (size_t)BQ * NH * NTOK * HD;   // 17,301,504 elements
  unsigned short* qb  = (unsigned short*)d_ws;
  unsigned short* kb  = qb + QSZ;
  unsigned short* vb  = kb + QSZ;
  unsigned short* aob = vb + QSZ;
  unsigned short* xb  = aob + QSZ;                   // x bf16
  unsigned short* wb  = xb + QSZ;                    // w_qkv bf16 (786432)
  unsigned short* wpb = wb + 786432;                 // w_proj bf16 (262144)
  float* out0 = (float*)d_out;                       // [B][N][C]
  float* out1 = out0 + (size_t)BQ * NTOK * CDIM;     // [B][8192][256]

  to_bf16_3<<<8960, 256, 0, stream>>>(x, xb, 2162688, w_qkv, wb, 98304, w_proj, wpb, 32768);
  qkv_mfma<<<dim3(12, 264), 256, 0, stream>>>(xb, wb, qb, kb, vb);
  attn_pm<<<320, 512, 0, stream>>>(qb, kb, vb, aob, out1);
  proj_mfma<<<dim3(4, 264), 256, 0, stream>>>(aob, wpb, b_proj, out0);
}